// Round 1
// baseline (186.209 us; speedup 1.0000x reference)
//
#include <hip/hip_runtime.h>

// Problem constants (from reference)
#define BB 16
#define WW 256
#define SS 512
#define FF 768
#define LL 4
#define EE 256
#define NW (WW - 1)   // 255 words with spans (slot 0 = root, zeros)

// One block per (b, w) output row.
// wave 0 (threads 0..63):   copy word embedding row (E=256 floats = 64 float4)
// waves 1-3 (threads 64..255, 192 lanes): each owns one float4 column of F=768,
//   accumulating softmax(layer_weights)[l] * layers[l,b,s,f] over the span,
//   scaled by gamma/len.
__global__ __launch_bounds__(256) void bert_lexer_fused(
    const int*   __restrict__ word_indices,   // [B, W]
    const int*   __restrict__ span_starts,    // [B, NW]
    const int*   __restrict__ span_ends,      // [B, NW]
    const float* __restrict__ emb_table,      // [V, E]
    const float* __restrict__ layers,         // [L, B, S, F]
    const float* __restrict__ layer_weights,  // [L]
    const float* __restrict__ gamma,          // [1]
    float*       __restrict__ out)            // [B, W, E+F]
{
    const int bw = blockIdx.x;        // 0 .. B*W-1
    const int b  = bw / WW;
    const int w  = bw % WW;
    const int t  = threadIdx.x;

    float* outrow = out + (size_t)bw * (EE + FF);

    if (t < 64) {
        // ---- word embedding gather: 64 lanes x float4 = 256 floats ----
        const int idx = word_indices[bw];
        const float4* src = (const float4*)(emb_table + (size_t)idx * EE);
        ((float4*)outrow)[t] = src[t];
    } else {
        // ---- bert weighted span-mean: 192 lanes x float4 = 768 floats ----
        const int c = t - 64;   // float4 column index in [0, 192)

        // softmax(layer_weights) — L=4, computed redundantly per thread
        const float l0 = layer_weights[0];
        const float l1 = layer_weights[1];
        const float l2 = layer_weights[2];
        const float l3 = layer_weights[3];
        const float m  = fmaxf(fmaxf(l0, l1), fmaxf(l2, l3));
        const float e0 = expf(l0 - m);
        const float e1 = expf(l1 - m);
        const float e2 = expf(l2 - m);
        const float e3 = expf(l3 - m);
        const float inv = 1.0f / (e0 + e1 + e2 + e3);
        float wsm[LL] = { e0 * inv, e1 * inv, e2 * inv, e3 * inv };
        const float g = gamma[0];

        float4 acc = make_float4(0.f, 0.f, 0.f, 0.f);
        if (w > 0) {
            const int i  = w - 1;
            const int st = span_starts[b * NW + i];
            const int en = span_ends[b * NW + i];
            const int len = en - st;
            if (len > 0) {
#pragma unroll
                for (int l = 0; l < LL; ++l) {
                    const float wl = wsm[l];
                    const float* base = layers + (((size_t)l * BB + b) * SS) * FF;
                    for (int s = st; s < en; ++s) {
                        const float4 v = ((const float4*)(base + (size_t)s * FF))[c];
                        acc.x += wl * v.x;
                        acc.y += wl * v.y;
                        acc.z += wl * v.z;
                        acc.w += wl * v.w;
                    }
                }
                const float scale = g / (float)len;
                acc.x *= scale; acc.y *= scale; acc.z *= scale; acc.w *= scale;
            }
        }
        // unconditional write: zeros for root slot / empty spans (poison-safe)
        ((float4*)(outrow + EE))[c] = acc;
    }
}

extern "C" void kernel_launch(void* const* d_in, const int* in_sizes, int n_in,
                              void* d_out, int out_size, void* d_ws, size_t ws_size,
                              hipStream_t stream) {
    const int*   word_indices  = (const int*)d_in[0];
    const int*   span_starts   = (const int*)d_in[1];
    const int*   span_ends     = (const int*)d_in[2];
    const float* emb_table     = (const float*)d_in[3];
    const float* layers        = (const float*)d_in[4];
    const float* layer_weights = (const float*)d_in[5];
    const float* gamma         = (const float*)d_in[6];
    float*       out           = (float*)d_out;

    dim3 grid(BB * WW);
    dim3 block(256);
    hipLaunchKernelGGL(bert_lexer_fused, grid, block, 0, stream,
                       word_indices, span_starts, span_ends,
                       emb_table, layers, layer_weights, gamma, out);
}